// Round 5
// baseline (304.002 us; speedup 1.0000x reference)
//
#include <hip/hip_runtime.h>
#include <hip/hip_bf16.h>
#include <math.h>

#define HIDDEN 1024
#define HEADS 16
#define HEAD_DIM 64
#define EPS 1e-5f

typedef __attribute__((ext_vector_type(8))) short bf16x8;
typedef __attribute__((ext_vector_type(4))) float f32x4;

#if defined(__has_builtin)
#if __has_builtin(__builtin_amdgcn_exp2f)
#define EXP2(x) __builtin_amdgcn_exp2f(x)
#endif
#endif
#ifndef EXP2
#define EXP2(x) exp2f(x)
#endif

// 0.125 (1/sqrt(64)) * log2(e): folded into Wq/bq so softmax is exp2(s)
#define QSCALE 0.18033688011112042f

__device__ __forceinline__ short f2bf(float f) {
    union { float f; unsigned u; } v; v.f = f;
    unsigned r = v.u + 0x7fffu + ((v.u >> 16) & 1u);   // RNE
    return (short)(r >> 16);
}

// async global->LDS DMA, 16 B per lane; dest = ldsbase + lane*16
__device__ __forceinline__ void gl_lds16(const void* g, void* l) {
    __builtin_amdgcn_global_load_lds(
        (const __attribute__((address_space(1))) void*)g,
        (__attribute__((address_space(3))) void*)l, 16, 0, 0);
}

// ---------------------------------------------------------------------------
// Fused prep: [0,4096) cast X->bf16; [4096,8192) transpose+cast 4 weights;
// [8192,8204) concat biases.
// ---------------------------------------------------------------------------
__global__ __launch_bounds__(256) void prep_kernel(
    const float* __restrict__ X,
    const float* __restrict__ Wq, const float* __restrict__ Wk,
    const float* __restrict__ Wv, const float* __restrict__ Wo,
    const float* __restrict__ bq, const float* __restrict__ bk,
    const float* __restrict__ bv,
    short* __restrict__ Xb, short* __restrict__ Wt3, short* __restrict__ Wot,
    float* __restrict__ b3)
{
    __shared__ short tile[32][33];
    const int id = blockIdx.x;
    if (id < 4096) {
        int i = id * 1024 + threadIdx.x * 4;
        float4 v = *(const float4*)(X + i);
        short o[4] = { f2bf(v.x), f2bf(v.y), f2bf(v.z), f2bf(v.w) };
        *(uint2*)(Xb + i) = *(uint2*)o;
    } else if (id < 8192) {
        int t = id - 4096;
        const int wsel = t >> 10; t &= 1023;
        const float* W = (wsel == 0) ? Wq : (wsel == 1) ? Wk : (wsel == 2) ? Wv : Wo;
        short* dst = (wsel < 3) ? (Wt3 + (size_t)wsel * 1024 * 1024) : Wot;
        const float scale = (wsel == 0) ? QSCALE : 1.0f;
        int n0 = (t & 31) * 32;
        int k0 = (t >> 5) * 32;
        int tx = threadIdx.x & 31;
        int ty = threadIdx.x >> 5;  // 0..7
        #pragma unroll
        for (int i = 0; i < 32; i += 8)
            tile[ty + i][tx] = f2bf(W[(size_t)(k0 + ty + i) * 1024 + n0 + tx] * scale);
        __syncthreads();
        #pragma unroll
        for (int i = 0; i < 32; i += 8)
            dst[(size_t)(n0 + ty + i) * 1024 + k0 + tx] = tile[tx][ty + i];
    } else {
        int i = (id - 8192) * 256 + threadIdx.x;
        if (i < 3072) {
            float v = (i < 1024) ? bq[i] * QSCALE
                    : (i < 2048) ? bk[i - 1024] : bv[i - 2048];
            b3[i] = v;
        }
    }
}

// ---------------------------------------------------------------------------
// C[M,N] = A[M,K] @ Bt[N,K]^T + bias[col] (+ resid fp32 if given).
// 128x128 tile, BK=32, 4 waves, global_load_lds staging, XOR-swizzled cols.
// Columns >= split_col go to C1 (rebased), else C0.
// ---------------------------------------------------------------------------
__global__ __launch_bounds__(256) void gemm_bt_mfma(
    const short* __restrict__ A, const short* __restrict__ Bt,
    const float* __restrict__ bias,
    void* __restrict__ C0, int ldc0,
    void* __restrict__ C1, int split_col, int ldc1,
    const float* __restrict__ resid,
    int M, int N, int K, int out_bf16)
{
    __shared__ short As[128 * 32];
    __shared__ short Bs[128 * 32];
    const int tid = threadIdx.x;
    const int wave = tid >> 6, lane = tid & 63;
    const int ln16 = lane & 15, quad = lane >> 4;
    const int wm = (wave >> 1) * 64, wn = (wave & 1) * 64;
    const int brow = blockIdx.y * 128, bcol = blockIdx.x * 128;

    const int sr  = lane >> 2;   // 0..15 row within 16-row chunk
    const int scb = lane & 3;    // lds col-block (8 shorts)

    f32x4 acc[4][4];
    #pragma unroll
    for (int mt = 0; mt < 4; ++mt)
        #pragma unroll
        for (int nt = 0; nt < 4; ++nt) acc[mt][nt] = (f32x4){0.f, 0.f, 0.f, 0.f};

    for (int k0 = 0; k0 < K; k0 += 32) {
        __syncthreads();
        #pragma unroll
        for (int i = 0; i < 2; ++i) {
            int rb = i * 64 + wave * 16;          // chunk base row (wave-uniform)
            int r  = rb + sr;
            int csrc = (scb ^ ((r >> 1) & 3)) * 8;
            gl_lds16(A  + (size_t)(brow + r) * K + k0 + csrc, &As[rb * 32]);
            gl_lds16(Bt + (size_t)(bcol + r) * K + k0 + csrc, &Bs[rb * 32]);
        }
        __syncthreads();

        bf16x8 af[4], bf[4];
        #pragma unroll
        for (int mt = 0; mt < 4; ++mt) {
            int r = wm + mt * 16 + ln16;
            af[mt] = *(const bf16x8*)&As[r * 32 + ((quad ^ ((r >> 1) & 3)) * 8)];
        }
        #pragma unroll
        for (int nt = 0; nt < 4; ++nt) {
            int r = wn + nt * 16 + ln16;
            bf[nt] = *(const bf16x8*)&Bs[r * 32 + ((quad ^ ((r >> 1) & 3)) * 8)];
        }
        #pragma unroll
        for (int mt = 0; mt < 4; ++mt)
            #pragma unroll
            for (int nt = 0; nt < 4; ++nt)
                acc[mt][nt] = __builtin_amdgcn_mfma_f32_16x16x32_bf16(
                    af[mt], bf[nt], acc[mt][nt], 0, 0, 0);
    }

    void* Cp = C0; int ld = ldc0; int coff = 0;
    if (bcol >= split_col) { Cp = C1; ld = ldc1; coff = split_col; }

    #pragma unroll
    for (int mt = 0; mt < 4; ++mt) {
        #pragma unroll
        for (int r = 0; r < 4; ++r) {
            int row = brow + wm + mt * 16 + quad * 4 + r;
            #pragma unroll
            for (int nt = 0; nt < 4; ++nt) {
                int col = bcol + wn + nt * 16 + ln16;
                float v = acc[mt][nt][r] + bias[col];
                if (resid) v += resid[(size_t)row * N + col];
                if (out_bf16) ((short*)Cp)[(size_t)row * ld + (col - coff)] = f2bf(v);
                else          ((float*)Cp)[(size_t)row * ld + (col - coff)] = v;
            }
        }
    }
}

// ---------------------------------------------------------------------------
// Vb[4096][1024] bf16 -> VT[1024][4096] bf16, 64x64 tiles
// ---------------------------------------------------------------------------
__global__ __launch_bounds__(256) void vtranspose_kernel(
    const short* __restrict__ Vb, short* __restrict__ VT)
{
    __shared__ short t[64][72];
    const int c0 = blockIdx.x * 64;    // feature block
    const int r0 = blockIdx.y * 64;    // token block
    const int tid = threadIdx.x;
    #pragma unroll
    for (int i = 0; i < 2; ++i) {
        int idx = tid + i * 256;
        int r = idx >> 3, cc = (idx & 7) * 8;
        *(uint4*)&t[r][cc] = *(const uint4*)(Vb + (size_t)(r0 + r) * 1024 + c0 + cc);
    }
    __syncthreads();
    #pragma unroll
    for (int i = 0; i < 2; ++i) {
        int idx = tid + i * 256;
        int c = idx >> 3, rr = (idx & 7) * 8;
        short tmp[8];
        #pragma unroll
        for (int j = 0; j < 8; ++j) tmp[j] = t[rr + j][c];
        *(uint4*)(VT + (size_t)(c0 + c) * 4096 + r0 + rr) = *(uint4*)tmp;
    }
}

// ---------------------------------------------------------------------------
// Barrier-free MFMA flash attention, fixed-max softmax (p = exp2(s); scale
// pre-folded into Wq/bq).  QKb[4096][2048]: Q cols 0..1023, K 1024..2047.
// VT[1024][4096] = V^T.  Block = (h, qt, b); 4 independent waves, each owns
// 32 q-rows.  K/V MFMA fragments are loaded DIRECTLY global->register
// (L2-resident streams; h-major grid keeps 2 heads/XCD).  LDS holds only the
// per-wave-private P round-trip, so the k-loop has NO __syncthreads at all.
// S^T trick (A=K, B=Q) -> b64 P writes / b128 P reads.  Row-sum l via
// ones-fragment MFMA.
// ---------------------------------------------------------------------------
__global__ __launch_bounds__(256) void attn_mfma_kernel(
    const short* __restrict__ QKb, const short* __restrict__ VT,
    short* __restrict__ Ctx)
{
    const int S = 2048;
    const int h = blockIdx.x, qt = blockIdx.y, b = blockIdx.z;
    const int tid = threadIdx.x;
    const int wave = tid >> 6, lane = tid & 63;
    const int ln16 = lane & 15, quad = lane >> 4;

    __shared__ short Ps[128 * 72];   // per-wave-private 32-row slices

    const int q0 = qt * 128 + wave * 32;

    // Q fragments (B-operand), straight from global, live in registers
    bf16x8 qfrag[2][2];
    #pragma unroll
    for (int qg = 0; qg < 2; ++qg)
        #pragma unroll
        for (int kb = 0; kb < 2; ++kb)
            qfrag[qg][kb] = *(const bf16x8*)(QKb +
                (size_t)(b * S + q0 + qg * 16 + ln16) * 2048 + h * 64 + kb * 32 + quad * 8);

    bf16x8 ones;
    #pragma unroll
    for (int j = 0; j < 8; ++j) ones[j] = (short)0x3F80;  // bf16 1.0

    f32x4 of[2][4], lacc[2];
    #pragma unroll
    for (int qg = 0; qg < 2; ++qg) {
        lacc[qg] = (f32x4){0.f, 0.f, 0.f, 0.f};
        #pragma unroll
        for (int nt = 0; nt < 4; ++nt) of[qg][nt] = (f32x4){0.f, 0.f, 0.f, 0.f};
    }

    // lane-exact fragment base pointers
    // K (A-operand of S^T): row = k-token (nt*16+ln16), col = kb*32+quad*8
    const short* krow = QKb + (size_t)(b * S + ln16) * 2048 + 1024 + h * 64 + quad * 8;
    // V^T (B-operand of PV): row = d (nt*16+ln16), col = k-token (kb*32+quad*8)
    const short* vrow = VT + (size_t)(h * 64 + ln16) * 4096 + b * S + quad * 8;
    short* pbase = &Ps[(wave * 32 + ln16) * 72];

    for (int kt = 0; kt < S / 64; ++kt) {
        // direct global->register K fragments for this 64-k tile
        bf16x8 kf[4][2];
        #pragma unroll
        for (int nt = 0; nt < 4; ++nt)
            #pragma unroll
            for (int kb = 0; kb < 2; ++kb)
                kf[nt][kb] = *(const bf16x8*)(krow +
                    (size_t)(kt * 64 + nt * 16) * 2048 + kb * 32);
        bf16x8 vf[4][2];
        #pragma unroll
        for (int nt = 0; nt < 4; ++nt)
            #pragma unroll
            for (int kb = 0; kb < 2; ++kb)
                vf[nt][kb] = *(const bf16x8*)(vrow +
                    (size_t)nt * 16 * 4096 + kt * 64 + kb * 32);

        // S^T = K Q^T ; exp2 ; pack 4 consecutive-k bf16 -> b64 write
        #pragma unroll
        for (int nt = 0; nt < 4; ++nt) {
            #pragma unroll
            for (int qg = 0; qg < 2; ++qg) {
                f32x4 a = (f32x4){0.f, 0.f, 0.f, 0.f};
                a = __builtin_amdgcn_mfma_f32_16x16x32_bf16(kf[nt][0], qfrag[qg][0], a, 0, 0, 0);
                a = __builtin_amdgcn_mfma_f32_16x16x32_bf16(kf[nt][1], qfrag[qg][1], a, 0, 0, 0);
                float p0 = EXP2(a[0]), p1 = EXP2(a[1]);
                float p2 = EXP2(a[2]), p3 = EXP2(a[3]);
                union { __hip_bfloat162 h2; unsigned u; } c01, c23;
                c01.h2 = __float22bfloat162_rn(make_float2(p0, p1));
                c23.h2 = __float22bfloat162_rn(make_float2(p2, p3));
                uint2 w; w.x = c01.u; w.y = c23.u;
                *(uint2*)(pbase + qg * 16 * 72 + nt * 16 + quad * 4) = w;
            }
        }

        // P fragments (per-wave private region: only lgkmcnt wait, no barrier)
        bf16x8 pf[2][2];
        #pragma unroll
        for (int qg = 0; qg < 2; ++qg)
            #pragma unroll
            for (int kb = 0; kb < 2; ++kb)
                pf[qg][kb] = *(const bf16x8*)(pbase + qg * 16 * 72 + kb * 32 + quad * 8);

        #pragma unroll
        for (int qg = 0; qg < 2; ++qg) {
            lacc[qg] = __builtin_amdgcn_mfma_f32_16x16x32_bf16(pf[qg][0], ones, lacc[qg], 0, 0, 0);
            lacc[qg] = __builtin_amdgcn_mfma_f32_16x16x32_bf16(pf[qg][1], ones, lacc[qg], 0, 0, 0);
        }
        #pragma unroll
        for (int nt = 0; nt < 4; ++nt)
            #pragma unroll
            for (int qg = 0; qg < 2; ++qg) {
                of[qg][nt] = __builtin_amdgcn_mfma_f32_16x16x32_bf16(pf[qg][0], vf[nt][0], of[qg][nt], 0, 0, 0);
                of[qg][nt] = __builtin_amdgcn_mfma_f32_16x16x32_bf16(pf[qg][1], vf[nt][1], of[qg][nt], 0, 0, 0);
            }
    }

    #pragma unroll
    for (int qg = 0; qg < 2; ++qg) {
        #pragma unroll
        for (int r = 0; r < 4; ++r) {
            float inv = 1.f / lacc[qg][r];
            int row = b * S + qt * 128 + wave * 32 + qg * 16 + quad * 4 + r;
            #pragma unroll
            for (int nt = 0; nt < 4; ++nt)
                Ctx[(size_t)row * 1024 + h * 64 + nt * 16 + ln16] =
                    f2bf(of[qg][nt][r] * inv);
        }
    }
}

// ---------------------------------------------------------------------------
// out = LayerNorm(x) * gamma + beta (residual already folded into x).
// One block per row; exactly one float4 per thread.
// ---------------------------------------------------------------------------
__global__ __launch_bounds__(256) void resln_kernel(
    const float* __restrict__ xin, const float* __restrict__ gamma,
    const float* __restrict__ beta, float* __restrict__ out)
{
    const int row = blockIdx.x;
    const int tid = threadIdx.x;
    const int wid = tid >> 6, lane = tid & 63;
    __shared__ float red[8];

    float4 x = *(const float4*)(xin + (size_t)row * HIDDEN + tid * 4);
    float s = x.x + x.y + x.z + x.w;
    #pragma unroll
    for (int off = 32; off > 0; off >>= 1) s += __shfl_xor(s, off, 64);
    if (lane == 0) red[wid] = s;
    __syncthreads();
    float mu = (red[0] + red[1] + red[2] + red[3]) * (1.f / HIDDEN);

    float dx = x.x - mu, dy = x.y - mu, dz = x.z - mu, dw = x.w - mu;
    float v = dx * dx + dy * dy + dz * dz + dw * dw;
    #pragma unroll
    for (int off = 32; off > 0; off >>= 1) v += __shfl_xor(v, off, 64);
    if (lane == 0) red[4 + wid] = v;
    __syncthreads();
    float var = (red[4] + red[5] + red[6] + red[7]) * (1.f / HIDDEN);
    float rstd = rsqrtf(var + EPS);

    float4 g = *(const float4*)(gamma + tid * 4);
    float4 bt = *(const float4*)(beta + tid * 4);
    float4 o;
    o.x = dx * rstd * g.x + bt.x;
    o.y = dy * rstd * g.y + bt.y;
    o.z = dz * rstd * g.z + bt.z;
    o.w = dw * rstd * g.w + bt.w;
    *(float4*)(out + (size_t)row * HIDDEN + tid * 4) = o;
}

// ---------------------------------------------------------------------------
extern "C" void kernel_launch(void* const* d_in, const int* in_sizes, int n_in,
                              void* d_out, int out_size, void* d_ws, size_t ws_size,
                              hipStream_t stream)
{
    const float* X     = (const float*)d_in[0];
    const float* Wq    = (const float*)d_in[1];
    const float* bq    = (const float*)d_in[2];
    const float* Wk    = (const float*)d_in[3];
    const float* bk    = (const float*)d_in[4];
    const float* Wv    = (const float*)d_in[5];
    const float* bv    = (const float*)d_in[6];
    const float* Wo    = (const float*)d_in[7];
    const float* bo    = (const float*)d_in[8];
    const float* gamma = (const float*)d_in[9];
    const float* beta  = (const float*)d_in[10];
    float* out = (float*)d_out;

    const int B = 2, S = 2048;
    const int M = B * S;                       // 4096
    const size_t mat = (size_t)M * HIDDEN;     // 4M elems

    // workspace map (peak 41 MB):
    //   [0,8)    Xb (dead after QKV gemm) -> VT overlays
    //   [8,10)   Wot
    //   [10,16)  Wt3 (3072x1024 bf16)
    //   [16,17)  b3
    //   [17,33)  QKb (dead after attn) -> Pj (fp32) overlays
    //   [33,41)  Vb (dead after vtrans) -> Ctx overlays
    char* ws = (char*)d_ws;
    short* Xb  = (short*)(ws);
    short* VT  = (short*)(ws);
    short* Wot = (short*)(ws + (8ull << 20));
    short* Wt3 = (short*)(ws + (10ull << 20));
    float* b3  = (float*)(ws + (16ull << 20));
    short* QKb = (short*)(ws + (17ull << 20));
    float* Pj  = (float*)(ws + (17ull << 20));
    short* Vb  = (short*)(ws + (33ull << 20));
    short* Ctx = (short*)(ws + (33ull << 20));

    dim3 blk(256);

    prep_kernel<<<dim3(8204), blk, 0, stream>>>(X, Wq, Wk, Wv, Wo, bq, bk, bv,
                                                Xb, Wt3, Wot, b3);

    // fused QKV projection: N=3072, V columns routed to Vb
    dim3 qkvgrid(3072 / 128, M / 128);         // (24, 32) = 768 blocks
    gemm_bt_mfma<<<qkvgrid, blk, 0, stream>>>(Xb, Wt3, b3,
                                              QKb, 2048, Vb, 2048, 1024,
                                              nullptr, M, 3072, HIDDEN, 1);

    vtranspose_kernel<<<dim3(16, 64), blk, 0, stream>>>(Vb, VT);

    dim3 agrid(HEADS, S / 128, B);             // (16, 16, 2) = 512 blocks
    attn_mfma_kernel<<<agrid, blk, 0, stream>>>(QKb, VT, Ctx);

    // output projection + bias + residual (fp32 out)
    dim3 ogrid(HIDDEN / 128, M / 128);         // (8, 32)
    gemm_bt_mfma<<<ogrid, blk, 0, stream>>>(Ctx, Wot, bo,
                                            Pj, 1024, nullptr, 1 << 30, 0,
                                            X, M, HIDDEN, HIDDEN, 0);

    resln_kernel<<<M, blk, 0, stream>>>(Pj, gamma, beta, out);
}

// Round 6
// 243.790 us; speedup vs baseline: 1.2470x; 1.2470x over previous
//
#include <hip/hip_runtime.h>
#include <hip/hip_bf16.h>
#include <math.h>

#define HIDDEN 1024
#define HEADS 16
#define HEAD_DIM 64
#define EPS 1e-5f

typedef __attribute__((ext_vector_type(8))) short bf16x8;
typedef __attribute__((ext_vector_type(4))) float f32x4;

#if defined(__has_builtin)
#if __has_builtin(__builtin_amdgcn_exp2f)
#define EXP2(x) __builtin_amdgcn_exp2f(x)
#endif
#endif
#ifndef EXP2
#define EXP2(x) exp2f(x)
#endif

// 0.125 (1/sqrt(64)) * log2(e): folded into Wq/bq so softmax is exp2(s)
#define QSCALE 0.18033688011112042f

__device__ __forceinline__ short f2bf(float f) {
    union { float f; unsigned u; } v; v.f = f;
    unsigned r = v.u + 0x7fffu + ((v.u >> 16) & 1u);   // RNE
    return (short)(r >> 16);
}

// async global->LDS DMA, 16 B per lane; dest = ldsbase + lane*16
__device__ __forceinline__ void gl_lds16(const void* g, void* l) {
    __builtin_amdgcn_global_load_lds(
        (const __attribute__((address_space(1))) void*)g,
        (__attribute__((address_space(3))) void*)l, 16, 0, 0);
}

// ---------------------------------------------------------------------------
// Fused prep: [0,4096) cast X->bf16; [4096,8192) transpose+cast 4 weights;
// [8192,8204) concat biases.
// ---------------------------------------------------------------------------
__global__ __launch_bounds__(256) void prep_kernel(
    const float* __restrict__ X,
    const float* __restrict__ Wq, const float* __restrict__ Wk,
    const float* __restrict__ Wv, const float* __restrict__ Wo,
    const float* __restrict__ bq, const float* __restrict__ bk,
    const float* __restrict__ bv,
    short* __restrict__ Xb, short* __restrict__ Wt3, short* __restrict__ Wot,
    float* __restrict__ b3)
{
    __shared__ short tile[32][33];
    const int id = blockIdx.x;
    if (id < 4096) {
        int i = id * 1024 + threadIdx.x * 4;
        float4 v = *(const float4*)(X + i);
        short o[4] = { f2bf(v.x), f2bf(v.y), f2bf(v.z), f2bf(v.w) };
        *(uint2*)(Xb + i) = *(uint2*)o;
    } else if (id < 8192) {
        int t = id - 4096;
        const int wsel = t >> 10; t &= 1023;
        const float* W = (wsel == 0) ? Wq : (wsel == 1) ? Wk : (wsel == 2) ? Wv : Wo;
        short* dst = (wsel < 3) ? (Wt3 + (size_t)wsel * 1024 * 1024) : Wot;
        const float scale = (wsel == 0) ? QSCALE : 1.0f;
        int n0 = (t & 31) * 32;
        int k0 = (t >> 5) * 32;
        int tx = threadIdx.x & 31;
        int ty = threadIdx.x >> 5;  // 0..7
        #pragma unroll
        for (int i = 0; i < 32; i += 8)
            tile[ty + i][tx] = f2bf(W[(size_t)(k0 + ty + i) * 1024 + n0 + tx] * scale);
        __syncthreads();
        #pragma unroll
        for (int i = 0; i < 32; i += 8)
            dst[(size_t)(n0 + ty + i) * 1024 + k0 + tx] = tile[tx][ty + i];
    } else {
        int i = (id - 8192) * 256 + threadIdx.x;
        if (i < 3072) {
            float v = (i < 1024) ? bq[i] * QSCALE
                    : (i < 2048) ? bk[i - 1024] : bv[i - 2048];
            b3[i] = v;
        }
    }
}

// ---------------------------------------------------------------------------
// C[M,N] = A[M,K] @ Bt[N,K]^T + bias[col] (+ resid fp32 if given).
// 128x128 tile, BK=32, 4 waves.  Double-buffered global_load_lds staging,
// ONE barrier per k-iter: DMA(k+1) issued right after the barrier, lands
// during compute(k), drained by the next barrier.  XOR-swizzled columns.
// Columns >= split_col go to C1 (rebased), else C0.
// ---------------------------------------------------------------------------
__global__ __launch_bounds__(256) void gemm_bt_mfma(
    const short* __restrict__ A, const short* __restrict__ Bt,
    const float* __restrict__ bias,
    void* __restrict__ C0, int ldc0,
    void* __restrict__ C1, int split_col, int ldc1,
    const float* __restrict__ resid,
    int M, int N, int K, int out_bf16)
{
    __shared__ short As[2][128 * 32];
    __shared__ short Bs[2][128 * 32];
    const int tid = threadIdx.x;
    const int wave = tid >> 6, lane = tid & 63;
    const int ln16 = lane & 15, quad = lane >> 4;
    const int wm = (wave >> 1) * 64, wn = (wave & 1) * 64;
    const int brow = blockIdx.y * 128, bcol = blockIdx.x * 128;

    const int sr  = lane >> 2;   // 0..15 row within 16-row chunk
    const int scb = lane & 3;    // lds col-block (8 shorts)

    f32x4 acc[4][4];
    #pragma unroll
    for (int mt = 0; mt < 4; ++mt)
        #pragma unroll
        for (int nt = 0; nt < 4; ++nt) acc[mt][nt] = (f32x4){0.f, 0.f, 0.f, 0.f};

    // stage tile at k0 into buffer buf
    #define GSTAGE(k0_, buf_)                                                   \
        {                                                                       \
            _Pragma("unroll")                                                   \
            for (int i = 0; i < 2; ++i) {                                       \
                int rb = i * 64 + wave * 16;                                    \
                int r  = rb + sr;                                               \
                int csrc = (scb ^ ((r >> 1) & 3)) * 8;                          \
                gl_lds16(A  + (size_t)(brow + r) * K + (k0_) + csrc,            \
                         &As[buf_][rb * 32]);                                   \
                gl_lds16(Bt + (size_t)(bcol + r) * K + (k0_) + csrc,            \
                         &Bs[buf_][rb * 32]);                                   \
            }                                                                   \
        }

    GSTAGE(0, 0);

    for (int k0 = 0; k0 < K; k0 += 32) {
        const int cur = (k0 >> 5) & 1;
        __syncthreads();                       // drains DMA for buf[cur]
        if (k0 + 32 < K) GSTAGE(k0 + 32, cur ^ 1);

        bf16x8 af[4], bf[4];
        #pragma unroll
        for (int mt = 0; mt < 4; ++mt) {
            int r = wm + mt * 16 + ln16;
            af[mt] = *(const bf16x8*)&As[cur][r * 32 + ((quad ^ ((r >> 1) & 3)) * 8)];
        }
        #pragma unroll
        for (int nt = 0; nt < 4; ++nt) {
            int r = wn + nt * 16 + ln16;
            bf[nt] = *(const bf16x8*)&Bs[cur][r * 32 + ((quad ^ ((r >> 1) & 3)) * 8)];
        }
        #pragma unroll
        for (int mt = 0; mt < 4; ++mt)
            #pragma unroll
            for (int nt = 0; nt < 4; ++nt)
                acc[mt][nt] = __builtin_amdgcn_mfma_f32_16x16x32_bf16(
                    af[mt], bf[nt], acc[mt][nt], 0, 0, 0);
    }
    #undef GSTAGE

    void* Cp = C0; int ld = ldc0; int coff = 0;
    if (bcol >= split_col) { Cp = C1; ld = ldc1; coff = split_col; }

    #pragma unroll
    for (int mt = 0; mt < 4; ++mt) {
        #pragma unroll
        for (int r = 0; r < 4; ++r) {
            int row = brow + wm + mt * 16 + quad * 4 + r;
            #pragma unroll
            for (int nt = 0; nt < 4; ++nt) {
                int col = bcol + wn + nt * 16 + ln16;
                float v = acc[mt][nt][r] + bias[col];
                if (resid) v += resid[(size_t)row * N + col];
                if (out_bf16) ((short*)Cp)[(size_t)row * ld + (col - coff)] = f2bf(v);
                else          ((float*)Cp)[(size_t)row * ld + (col - coff)] = v;
            }
        }
    }
}

// ---------------------------------------------------------------------------
// Vb[4096][1024] bf16 -> VT[1024][4096] bf16, 64x64 tiles
// ---------------------------------------------------------------------------
__global__ __launch_bounds__(256) void vtranspose_kernel(
    const short* __restrict__ Vb, short* __restrict__ VT)
{
    __shared__ short t[64][72];
    const int c0 = blockIdx.x * 64;    // feature block
    const int r0 = blockIdx.y * 64;    // token block
    const int tid = threadIdx.x;
    #pragma unroll
    for (int i = 0; i < 2; ++i) {
        int idx = tid + i * 256;
        int r = idx >> 3, cc = (idx & 7) * 8;
        *(uint4*)&t[r][cc] = *(const uint4*)(Vb + (size_t)(r0 + r) * 1024 + c0 + cc);
    }
    __syncthreads();
    #pragma unroll
    for (int i = 0; i < 2; ++i) {
        int idx = tid + i * 256;
        int c = idx >> 3, rr = (idx & 7) * 8;
        short tmp[8];
        #pragma unroll
        for (int j = 0; j < 8; ++j) tmp[j] = t[rr + j][c];
        *(uint4*)(VT + (size_t)(c0 + c) * 4096 + r0 + rr) = *(uint4*)tmp;
    }
}

// ---------------------------------------------------------------------------
// MFMA flash attention, fixed-max softmax (p = exp2(s); scale pre-folded).
// QKb[4096][2048]: Q cols 0..1023, K 1024..2047.  VT[1024][4096] = V^T.
// Block = (h, qt, b): 128 q-rows; 4 waves, wave owns 32 q-rows.  K/V tiles
// double-buffered via global_load_lds, ONE barrier per 64-k tile (DMA for
// kt+1 issued post-barrier, lands during compute of kt).  S^T trick
// (A=K, B=Q) -> b64 P writes / b128 P reads, P region per-wave-private.
// Row-sum l via ones-fragment MFMA.  h-major grid: 2 heads' K/V per XCD L2.
// ---------------------------------------------------------------------------
__global__ __launch_bounds__(256) void attn_mfma_kernel(
    const short* __restrict__ QKb, const short* __restrict__ VT,
    short* __restrict__ Ctx)
{
    const int S = 2048;
    const int h = blockIdx.x, qt = blockIdx.y, b = blockIdx.z;
    const int tid = threadIdx.x;
    const int wave = tid >> 6, lane = tid & 63;
    const int ln16 = lane & 15, quad = lane >> 4;

    __shared__ short Ks[2][64 * 64];   // [k-token][d], swizzled
    __shared__ short Vs[2][64 * 64];   // [d][k-token], swizzled
    __shared__ short Ps[128 * 72];     // [q][k-token], per-wave-private slices

    const int q0 = qt * 128 + wave * 32;

    // Q fragments (B-operand), straight from global, live in registers
    bf16x8 qfrag[2][2];
    #pragma unroll
    for (int qg = 0; qg < 2; ++qg)
        #pragma unroll
        for (int kb = 0; kb < 2; ++kb)
            qfrag[qg][kb] = *(const bf16x8*)(QKb +
                (size_t)(b * S + q0 + qg * 16 + ln16) * 2048 + h * 64 + kb * 32 + quad * 8);

    bf16x8 ones;
    #pragma unroll
    for (int j = 0; j < 8; ++j) ones[j] = (short)0x3F80;  // bf16 1.0

    f32x4 of[2][4], lacc[2];
    #pragma unroll
    for (int qg = 0; qg < 2; ++qg) {
        lacc[qg] = (f32x4){0.f, 0.f, 0.f, 0.f};
        #pragma unroll
        for (int nt = 0; nt < 4; ++nt) of[qg][nt] = (f32x4){0.f, 0.f, 0.f, 0.f};
    }

    const int sr  = lane >> 3;   // 0..7 row within 8-row chunk
    const int scb = lane & 7;    // lds col-block

    #define ASTAGE(kt_, buf_)                                                    \
        {                                                                        \
            _Pragma("unroll")                                                    \
            for (int i = 0; i < 2; ++i) {                                        \
                int ci = wave * 2 + i;                                           \
                int r  = ci * 8 + sr;                                            \
                int csrc = ((scb ^ (r & 7))) * 8;                                \
                gl_lds16(QKb + (size_t)(b * S + (kt_) * 64 + r) * 2048           \
                             + 1024 + h * 64 + csrc,                             \
                         &Ks[buf_][ci * 512]);                                   \
                gl_lds16(VT + (size_t)(h * 64 + r) * 4096                        \
                            + b * S + (kt_) * 64 + csrc,                         \
                         &Vs[buf_][ci * 512]);                                   \
            }                                                                    \
        }

    ASTAGE(0, 0);

    for (int kt = 0; kt < S / 64; ++kt) {
        const int cur = kt & 1;
        __syncthreads();                      // drains DMA for buf[cur]
        if (kt + 1 < S / 64) ASTAGE(kt + 1, cur ^ 1);

        // S^T = K Q^T ; exp2 ; pack 4 consecutive-k bf16 -> b64 write
        #pragma unroll
        for (int nt = 0; nt < 4; ++nt) {
            bf16x8 kf[2];
            #pragma unroll
            for (int kb = 0; kb < 2; ++kb) {
                int r = nt * 16 + ln16;
                int cb = (kb * 4 + quad) ^ (r & 7);
                kf[kb] = *(const bf16x8*)&Ks[cur][r * 64 + cb * 8];
            }
            #pragma unroll
            for (int qg = 0; qg < 2; ++qg) {
                f32x4 a = (f32x4){0.f, 0.f, 0.f, 0.f};
                a = __builtin_amdgcn_mfma_f32_16x16x32_bf16(kf[0], qfrag[qg][0], a, 0, 0, 0);
                a = __builtin_amdgcn_mfma_f32_16x16x32_bf16(kf[1], qfrag[qg][1], a, 0, 0, 0);
                float p0 = EXP2(a[0]), p1 = EXP2(a[1]);
                float p2 = EXP2(a[2]), p3 = EXP2(a[3]);
                union { __hip_bfloat162 h2; unsigned u; } c01, c23;
                c01.h2 = __float22bfloat162_rn(make_float2(p0, p1));
                c23.h2 = __float22bfloat162_rn(make_float2(p2, p3));
                uint2 w; w.x = c01.u; w.y = c23.u;
                *(uint2*)&Ps[(wave * 32 + qg * 16 + ln16) * 72 + nt * 16 + quad * 4] = w;
            }
        }

        // P fragments (per-wave private region: no barrier needed)
        bf16x8 pf[2][2];
        #pragma unroll
        for (int qg = 0; qg < 2; ++qg)
            #pragma unroll
            for (int kb = 0; kb < 2; ++kb)
                pf[qg][kb] = *(const bf16x8*)
                    &Ps[(wave * 32 + qg * 16 + ln16) * 72 + kb * 32 + quad * 8];

        #pragma unroll
        for (int qg = 0; qg < 2; ++qg) {
            lacc[qg] = __builtin_amdgcn_mfma_f32_16x16x32_bf16(pf[qg][0], ones, lacc[qg], 0, 0, 0);
            lacc[qg] = __builtin_amdgcn_mfma_f32_16x16x32_bf16(pf[qg][1], ones, lacc[qg], 0, 0, 0);
        }
        #pragma unroll
        for (int nt = 0; nt < 4; ++nt) {
            bf16x8 vf[2];
            #pragma unroll
            for (int kb = 0; kb < 2; ++kb) {
                int r = nt * 16 + ln16;
                int cb = (kb * 4 + quad) ^ (r & 7);
                vf[kb] = *(const bf16x8*)&Vs[cur][r * 64 + cb * 8];
            }
            #pragma unroll
            for (int qg = 0; qg < 2; ++qg) {
                of[qg][nt] = __builtin_amdgcn_mfma_f32_16x16x32_bf16(pf[qg][0], vf[0], of[qg][nt], 0, 0, 0);
                of[qg][nt] = __builtin_amdgcn_mfma_f32_16x16x32_bf16(pf[qg][1], vf[1], of[qg][nt], 0, 0, 0);
            }
        }
    }
    #undef ASTAGE

    #pragma unroll
    for (int qg = 0; qg < 2; ++qg) {
        #pragma unroll
        for (int r = 0; r < 4; ++r) {
            float inv = 1.f / lacc[qg][r];
            int row = b * S + qt * 128 + wave * 32 + qg * 16 + quad * 4 + r;
            #pragma unroll
            for (int nt = 0; nt < 4; ++nt)
                Ctx[(size_t)row * 1024 + h * 64 + nt * 16 + ln16] =
                    f2bf(of[qg][nt][r] * inv);
        }
    }
}

// ---------------------------------------------------------------------------
// out = LayerNorm(x) * gamma + beta (residual already folded into x).
// One block per row; exactly one float4 per thread.
// ---------------------------------------------------------------------------
__global__ __launch_bounds__(256) void resln_kernel(
    const float* __restrict__ xin, const float* __restrict__ gamma,
    const float* __restrict__ beta, float* __restrict__ out)
{
    const int row = blockIdx.x;
    const int tid = threadIdx.x;
    const int wid = tid >> 6, lane = tid & 63;
    __shared__ float red[8];

    float4 x = *(const float4*)(xin + (size_t)row * HIDDEN + tid * 4);
    float s = x.x + x.y + x.z + x.w;
    #pragma unroll
    for (int off = 32; off > 0; off >>= 1) s += __shfl_xor(s, off, 64);
    if (lane == 0) red[wid] = s;
    __syncthreads();
    float mu = (red[0] + red[1] + red[2] + red[3]) * (1.f / HIDDEN);

    float dx = x.x - mu, dy = x.y - mu, dz = x.z - mu, dw = x.w - mu;
    float v = dx * dx + dy * dy + dz * dz + dw * dw;
    #pragma unroll
    for (int off = 32; off > 0; off >>= 1) v += __shfl_xor(v, off, 64);
    if (lane == 0) red[4 + wid] = v;
    __syncthreads();
    float var = (red[4] + red[5] + red[6] + red[7]) * (1.f / HIDDEN);
    float rstd = rsqrtf(var + EPS);

    float4 g = *(const float4*)(gamma + tid * 4);
    float4 bt = *(const float4*)(beta + tid * 4);
    float4 o;
    o.x = dx * rstd * g.x + bt.x;
    o.y = dy * rstd * g.y + bt.y;
    o.z = dz * rstd * g.z + bt.z;
    o.w = dw * rstd * g.w + bt.w;
    *(float4*)(out + (size_t)row * HIDDEN + tid * 4) = o;
}

// ---------------------------------------------------------------------------
extern "C" void kernel_launch(void* const* d_in, const int* in_sizes, int n_in,
                              void* d_out, int out_size, void* d_ws, size_t ws_size,
                              hipStream_t stream)
{
    const float* X     = (const float*)d_in[0];
    const float* Wq    = (const float*)d_in[1];
    const float* bq    = (const float*)d_in[2];
    const float* Wk    = (const float*)d_in[3];
    const float* bk    = (const float*)d_in[4];
    const float* Wv    = (const float*)d_in[5];
    const float* bv    = (const float*)d_in[6];
    const float* Wo    = (const float*)d_in[7];
    const float* bo    = (const float*)d_in[8];
    const float* gamma = (const float*)d_in[9];
    const float* beta  = (const float*)d_in[10];
    float* out = (float*)d_out;

    const int B = 2, S = 2048;
    const int M = B * S;                       // 4096
    const size_t mat = (size_t)M * HIDDEN;     // 4M elems

    // workspace map (peak 41 MB):
    //   [0,8)    Xb (dead after QKV gemm) -> VT overlays
    //   [8,10)   Wot
    //   [10,16)  Wt3 (3072x1024 bf16)
    //   [16,17)  b3
    //   [17,33)  QKb (dead after attn) -> Pj (fp32) overlays
    //   [33,41)  Vb (dead after vtrans) -> Ctx overlays
    char* ws = (char*)d_ws;
    short* Xb  = (short*)(ws);
    short* VT  = (short*)(ws);
    short* Wot = (short*)(ws + (8ull << 20));
    short* Wt3 = (short*)(ws + (10ull << 20));
    float* b3  = (float*)(ws + (16ull << 20));
    short* QKb = (short*)(ws + (17ull << 20));
    float* Pj  = (float*)(ws + (17ull << 20));
    short* Vb  = (short*)(ws + (33ull << 20));
    short* Ctx = (short*)(ws + (33ull << 20));

    dim3 blk(256);

    prep_kernel<<<dim3(8204), blk, 0, stream>>>(X, Wq, Wk, Wv, Wo, bq, bk, bv,
                                                Xb, Wt3, Wot, b3);

    // fused QKV projection: N=3072, V columns routed to Vb
    dim3 qkvgrid(3072 / 128, M / 128);         // (24, 32) = 768 blocks
    gemm_bt_mfma<<<qkvgrid, blk, 0, stream>>>(Xb, Wt3, b3,
                                              QKb, 2048, Vb, 2048, 1024,
                                              nullptr, M, 3072, HIDDEN, 1);

    vtranspose_kernel<<<dim3(16, 64), blk, 0, stream>>>(Vb, VT);

    dim3 agrid(HEADS, S / 128, B);             // (16, 16, 2) = 512 blocks
    attn_mfma_kernel<<<agrid, blk, 0, stream>>>(QKb, VT, Ctx);

    // output projection + bias + residual (fp32 out)
    dim3 ogrid(HIDDEN / 128, M / 128);         // (8, 32)
    gemm_bt_mfma<<<ogrid, blk, 0, stream>>>(Ctx, Wot, bo,
                                            Pj, 1024, nullptr, 1 << 30, 0,
                                            X, M, HIDDEN, HIDDEN, 0);

    resln_kernel<<<M, blk, 0, stream>>>(Pj, gamma, beta, out);
}